// Round 14
// baseline (283.582 us; speedup 1.0000x reference)
//
#include <hip/hip_runtime.h>
#include <math.h>

#define HEADS 8
#define NEG 0.2f

typedef unsigned short ushort_t;
typedef __attribute__((ext_vector_type(8))) short short8;
typedef float f32x4 __attribute__((ext_vector_type(4)));

__device__ inline ushort_t f2bf(float f) {
  union { float f; unsigned u; } v; v.f = f;
  unsigned r = (v.u + 0x7FFF + ((v.u >> 16) & 1)) >> 16;  // RNE
  return (ushort_t)r;
}

__device__ inline float4 bf4(uint2 v) {
  union { unsigned u; float f; } a, b, c, d;
  a.u = v.x << 16; b.u = v.x & 0xffff0000u;
  c.u = v.y << 16; d.u = v.y & 0xffff0000u;
  return make_float4(a.f, b.f, c.f, d.f);
}

// fast ELU: exp(v)-1 via hw v_exp_f32; |abs err| ~1e-7, fine vs 1.7e-3 threshold
__device__ inline float elu_f(float v) {
  return (v > 0.f) ? v : (__expf(v) - 1.f);
}

// ------- fused init: zero accum buffers + x->bf16 + W1/W2 -> transposed bf16 -------
__global__ void init_k(int* __restrict__ ws, int zero_words,
                       const float* __restrict__ x, ushort_t* __restrict__ xb,
                       const float* __restrict__ W1, ushort_t* __restrict__ w1t,
                       const float* __restrict__ W2, ushort_t* __restrict__ w2t,
                       int nx4) {
  int i = blockIdx.x * blockDim.x + threadIdx.x;
  if (i < zero_words) ws[i] = 0;
  if (i < nx4) {
    float4 v = ((const float4*)x)[i];
    ushort_t o[4] = {f2bf(v.x), f2bf(v.y), f2bf(v.z), f2bf(v.w)};
    *(uint2*)&xb[i * 4] = *(uint2*)o;
  }
  if (i < 128 * 1024) {  // W1 [128][1024] -> w1t [1024][128]
    int n = i >> 7, k = i & 127;
    w1t[i] = f2bf(W1[(size_t)k * 1024 + n]);
  }
  if (i < 1024 * 512) {  // W2 [1024][512] -> w2t [512][1024]
    int n = i >> 10, k = i & 1023;
    w2t[i] = f2bf(W2[(size_t)k * 512 + n]);
  }
}

// -- edge prep + degree count + batch bounds fused (batch sorted; no atomics) --
__global__ void prep_k(const int* __restrict__ ei, int* __restrict__ src,
                       int* __restrict__ dst, int* __restrict__ deg,
                       const int* __restrict__ batch, int* __restrict__ bstart,
                       int* __restrict__ bend, int E, int Nn) {
  int i = blockIdx.x * blockDim.x + threadIdx.x;
  if (i < Nn) {
    int b = batch[i];
    if (i == 0 || batch[i - 1] != b) bstart[b] = i;
    if (i == Nn - 1 || batch[i + 1] != b) bend[b] = i + 1;
  }
  if (i >= E + Nn) return;
  int s, d;
  if (i < E) { s = ei[i]; d = ei[E + i]; }
  else       { s = d = i - E; }
  src[i] = s;
  dst[i] = d;
  atomicAdd(&deg[d], 1);
}

// single-block scan over N, 4 elems/thread (4096/chunk), wave-shuffle based
__global__ __launch_bounds__(1024) void scan_k(const int* __restrict__ deg,
                                               int* __restrict__ offs,
                                               int* __restrict__ cursor, int Nn) {
  __shared__ int wtot[16];
  __shared__ int wexcl[16];
  __shared__ int soff_s;
  int t = threadIdx.x;
  int lane = t & 63, w = t >> 6;
  if (t == 0) soff_s = 0;
  __syncthreads();
  for (int base = 0; base < Nn; base += 4096) {
    int idx = base + 4 * t;
    int4 v = make_int4(0, 0, 0, 0);
    if (idx + 3 < Nn) v = *(const int4*)&deg[idx];
    else {
      if (idx < Nn)     v.x = deg[idx];
      if (idx + 1 < Nn) v.y = deg[idx + 1];
      if (idx + 2 < Nn) v.z = deg[idx + 2];
      if (idx + 3 < Nn) v.w = deg[idx + 3];
    }
    int s1 = v.x, s2 = s1 + v.y, s3 = s2 + v.z, s4 = s3 + v.w;
    int sc = s4;  // wave-inclusive scan of per-thread totals
#pragma unroll
    for (int o = 1; o < 64; o <<= 1) {
      int x = __shfl_up(sc, o);
      if (lane >= o) sc += x;
    }
    if (lane == 63) wtot[w] = sc;
    __syncthreads();
    if (w == 0) {
      int tv = (lane < 16) ? wtot[lane] : 0;
      int ts = tv;
#pragma unroll
      for (int o = 1; o < 16; o <<= 1) {
        int x = __shfl_up(ts, o);
        if (lane >= o) ts += x;
      }
      if (lane < 16) wexcl[lane] = ts - tv;
      if (lane == 15) wtot[15] = ts;  // chunk total
    }
    __syncthreads();
    int excl = soff_s + wexcl[w] + (sc - s4);
    int o0 = excl, o1 = excl + s1, o2 = excl + s2, o3 = excl + s3;
    if (idx < Nn)     { offs[idx] = o0;     cursor[idx] = o0; }
    if (idx + 1 < Nn) { offs[idx + 1] = o1; cursor[idx + 1] = o1; }
    if (idx + 2 < Nn) { offs[idx + 2] = o2; cursor[idx + 2] = o2; }
    if (idx + 3 < Nn) { offs[idx + 3] = o3; cursor[idx + 3] = o3; }
    int chunk_total = wtot[15];
    __syncthreads();
    if (t == 0) soff_s += chunk_total;
    __syncthreads();
  }
  if (t == 0) offs[Nn] = soff_s;
}

// scatter src values directly into CSR slot order (no perm indirection)
__global__ void scatter_k(const int* __restrict__ src, const int* __restrict__ dst,
                          int* __restrict__ cursor, int* __restrict__ psrc, int Etot) {
  int i = blockIdx.x * blockDim.x + threadIdx.x;
  if (i >= Etot) return;
  int p = atomicAdd(&cursor[dst[i]], 1);
  psrc[p] = src[i];
}

// ------- bf16 MFMA GEMM + fused alpha epilogue: Cb[M,N](bf16) = A @ Bt^T -------
// 128x128 tile, 256 threads (4 waves 2x2), BK=64 (2 k-steps of 16x16x32 MFMA),
// register-prefetch software pipeline.
#define LDA 72  // padded LDS row stride (bf16 elems), 144B rows, 16B aligned
__global__ __launch_bounds__(256) void mfma_gemm_k(const ushort_t* __restrict__ A,
                                                   const ushort_t* __restrict__ Bt,
                                                   ushort_t* __restrict__ Cb,
                                                   const float* __restrict__ att_s,
                                                   const float* __restrict__ att_d,
                                                   float* __restrict__ asrc,
                                                   float* __restrict__ adst,
                                                   int M, int N, int K, int CSHIFT) {
  __shared__ ushort_t As[128 * LDA];
  __shared__ ushort_t Bs[128 * LDA];
  int tid = threadIdx.x;
  int lane = tid & 63;
  int wave = tid >> 6;
  int wm = (wave >> 1) * 64, wn = (wave & 1) * 64;
  int bm = blockIdx.y * 128, bn = blockIdx.x * 128;
  int lrow = lane & 15, lq = lane >> 4;

  f32x4 acc[4][4];
#pragma unroll
  for (int i = 0; i < 4; i++)
#pragma unroll
    for (int j = 0; j < 4; j++) acc[i][j] = 0.f;

  int srow = tid >> 2;          // 0..63
  int skc = (tid & 3) * 8;      // k elem offset within first 32 of BK

  int gr0 = min(bm + srow, M - 1);
  int gr1 = min(bm + srow + 64, M - 1);
  const ushort_t* pa0 = &A[(size_t)gr0 * K + skc];
  const ushort_t* pa1 = &A[(size_t)gr1 * K + skc];
  const ushort_t* pb0 = &Bt[(size_t)(bn + srow) * K + skc];
  const ushort_t* pb1 = &Bt[(size_t)(bn + srow + 64) * K + skc];

  short8 va0 = *(const short8*)pa0;
  short8 va1 = *(const short8*)(pa0 + 32);
  short8 va2 = *(const short8*)pa1;
  short8 va3 = *(const short8*)(pa1 + 32);
  short8 vb0 = *(const short8*)pb0;
  short8 vb1 = *(const short8*)(pb0 + 32);
  short8 vb2 = *(const short8*)pb1;
  short8 vb3 = *(const short8*)(pb1 + 32);

  for (int k0 = 0; k0 < K; k0 += 64) {
    __syncthreads();  // previous iter's fragment reads done before overwrite
    *(short8*)&As[srow * LDA + skc] = va0;
    *(short8*)&As[srow * LDA + 32 + skc] = va1;
    *(short8*)&As[(srow + 64) * LDA + skc] = va2;
    *(short8*)&As[(srow + 64) * LDA + 32 + skc] = va3;
    *(short8*)&Bs[srow * LDA + skc] = vb0;
    *(short8*)&Bs[srow * LDA + 32 + skc] = vb1;
    *(short8*)&Bs[(srow + 64) * LDA + skc] = vb2;
    *(short8*)&Bs[(srow + 64) * LDA + 32 + skc] = vb3;
    __syncthreads();
    if (k0 + 64 < K) {  // prefetch next chunk; completes during MFMA below
      int kn = k0 + 64;
      va0 = *(const short8*)(pa0 + kn);
      va1 = *(const short8*)(pa0 + kn + 32);
      va2 = *(const short8*)(pa1 + kn);
      va3 = *(const short8*)(pa1 + kn + 32);
      vb0 = *(const short8*)(pb0 + kn);
      vb1 = *(const short8*)(pb0 + kn + 32);
      vb2 = *(const short8*)(pb1 + kn);
      vb3 = *(const short8*)(pb1 + kn + 32);
    }
#pragma unroll
    for (int ks = 0; ks < 2; ks++) {
      short8 af[4], bfr[4];
#pragma unroll
      for (int t = 0; t < 4; t++) {
        af[t]  = *(const short8*)&As[(wm + t * 16 + lrow) * LDA + ks * 32 + lq * 8];
        bfr[t] = *(const short8*)&Bs[(wn + t * 16 + lrow) * LDA + ks * 32 + lq * 8];
      }
#pragma unroll
      for (int i = 0; i < 4; i++)
#pragma unroll
        for (int j = 0; j < 4; j++)
          acc[i][j] = __builtin_amdgcn_mfma_f32_16x16x32_bf16(af[i], bfr[j], acc[i][j], 0, 0, 0);
    }
  }

  // ---- fused alpha partials (fp32, pre-rounding) ----
  {
    int hh = (bn + wn) >> CSHIFT;
    float avs[4], avd[4];
#pragma unroll
    for (int j = 0; j < 4; j++) {
      int col = bn + wn + j * 16 + lrow;  // att [H][N/H] flat == column index
      avs[j] = att_s[col];
      avd[j] = att_d[col];
    }
#pragma unroll
    for (int i = 0; i < 4; i++) {
#pragma unroll
      for (int r = 0; r < 4; r++) {
        float ps = 0.f, pd = 0.f;
#pragma unroll
        for (int j = 0; j < 4; j++) {
          float v = acc[i][j][r];
          ps += v * avs[j];
          pd += v * avd[j];
        }
#pragma unroll
        for (int o = 1; o < 16; o <<= 1) {
          ps += __shfl_xor(ps, o);
          pd += __shfl_xor(pd, o);
        }
        int row = bm + wm + i * 16 + lq * 4 + r;
        if (lrow == 0 && row < M) {
          atomicAdd(&asrc[row * HEADS + hh], ps);
          atomicAdd(&adst[row * HEADS + hh], pd);
        }
      }
    }
  }

  // ---- bf16 store ----
#pragma unroll
  for (int i = 0; i < 4; i++) {
    int row0 = bm + wm + i * 16 + lq * 4;  // C/D: col=lane&15, row=(lane>>4)*4+reg
#pragma unroll
    for (int j = 0; j < 4; j++) {
      int col = bn + wn + j * 16 + lrow;
#pragma unroll
      for (int r = 0; r < 4; r++) {
        int row = row0 + r;
        if (row < M) Cb[(size_t)row * N + col] = f2bf(acc[i][j][r]);
      }
    }
  }
}

// ---- CSR aggregation: barrier-free, LDS-free, 16B uint4 gathers (8 ch/thread) ----
// One block per node, BT = F/8 threads; psrc reads block-uniform (HW broadcast);
// softmax weight via hw v_exp_f32; next batch's src ids prefetched while 8
// uint4 gathers (128 B/thread) are in flight. Per-channel accumulation order
// identical to the 4-ch version (same serial edge loop).
template <int F, int CSHIFT, int BT, typename OT>
__global__ __launch_bounds__(BT) void aggregate_k(const ushort_t* __restrict__ hb,
                                                  const float* __restrict__ asrc,
                                                  const float* __restrict__ adst,
                                                  const int* __restrict__ offs,
                                                  const int* __restrict__ psrc,
                                                  const float* __restrict__ bias,
                                                  OT* __restrict__ out) {
  static_assert(F == 8 * BT, "8 channels per thread");
  int n = blockIdx.x;
  int t = threadIdx.x;
  int c0 = 8 * t;
  int hh = c0 >> CSHIFT;
  float adn = adst[n * HEADS + hh];
  int e0 = offs[n], e1 = offs[n + 1];
  float acc[8] = {};
  float wsum = 0.f;

  int i = e0;
  int s[8];
  if (i + 8 <= e1) {
#pragma unroll
    for (int u = 0; u < 8; u++) s[u] = psrc[i + u];
  }
  while (i + 8 <= e1) {
    uint4 r[8];
    float av[8];
#pragma unroll
    for (int u = 0; u < 8; u++) r[u] = *(const uint4*)&hb[(size_t)s[u] * F + c0];
#pragma unroll
    for (int u = 0; u < 8; u++) av[u] = asrc[s[u] * HEADS + hh];
    i += 8;
    bool more = (i + 8 <= e1);
    int sn[8];
#pragma unroll
    for (int u = 0; u < 8; u++) sn[u] = more ? psrc[i + u] : 0;
#pragma unroll
    for (int u = 0; u < 8; u++) {
      float v = av[u] + adn;
      v = (v > 0.f) ? v : NEG * v;  // leaky_relu(0.2)
      float w = __expf(v);          // hw v_exp_f32; shift-invariant softmax
      float4 f0 = bf4(make_uint2(r[u].x, r[u].y));
      float4 f1 = bf4(make_uint2(r[u].z, r[u].w));
      wsum += w;
      acc[0] += w * f0.x; acc[1] += w * f0.y;
      acc[2] += w * f0.z; acc[3] += w * f0.w;
      acc[4] += w * f1.x; acc[5] += w * f1.y;
      acc[6] += w * f1.z; acc[7] += w * f1.w;
    }
#pragma unroll
    for (int u = 0; u < 8; u++) s[u] = sn[u];
  }
  for (; i < e1; i++) {
    int ss = psrc[i];
    float v = asrc[ss * HEADS + hh] + adn;
    v = (v > 0.f) ? v : NEG * v;
    float w = __expf(v);
    uint4 r = *(const uint4*)&hb[(size_t)ss * F + c0];
    float4 f0 = bf4(make_uint2(r.x, r.y));
    float4 f1 = bf4(make_uint2(r.z, r.w));
    wsum += w;
    acc[0] += w * f0.x; acc[1] += w * f0.y;
    acc[2] += w * f0.z; acc[3] += w * f0.w;
    acc[4] += w * f1.x; acc[5] += w * f1.y;
    acc[6] += w * f1.z; acc[7] += w * f1.w;
  }

  float inv = 1.f / wsum;
  float vv[8];
#pragma unroll
  for (int u = 0; u < 8; u++) vv[u] = elu_f(acc[u] * inv + bias[c0 + u]);
  if (sizeof(OT) == 2) {
    unsigned p[4];
#pragma unroll
    for (int u = 0; u < 4; u++)
      p[u] = (unsigned)f2bf(vv[2 * u]) | ((unsigned)f2bf(vv[2 * u + 1]) << 16);
    *(uint4*)&((ushort_t*)out)[(size_t)n * F + c0] = make_uint4(p[0], p[1], p[2], p[3]);
  } else {
    *(float4*)&((float*)out)[(size_t)n * F + c0] = make_float4(vv[0], vv[1], vv[2], vv[3]);
    *(float4*)&((float*)out)[(size_t)n * F + c0 + 4] = make_float4(vv[4], vv[5], vv[6], vv[7]);
  }
}

__global__ __launch_bounds__(256) void pool_k(const float* __restrict__ g,
                                              const int* __restrict__ batch,
                                              float* __restrict__ sums, int Nn) {
  int c = blockIdx.x * 256 + threadIdx.x;  // 0..511
  int n0 = blockIdx.y * 50;
  int n1 = min(n0 + 50, Nn);
  if (n0 >= n1) return;
  float acc = 0.f;
  int cur = batch[n0];
  for (int n = n0; n < n1; n++) {
    int b = batch[n];
    if (b != cur) { atomicAdd(&sums[cur * 512 + c], acc); acc = 0.f; cur = b; }
    acc += g[(size_t)n * 512 + c];
  }
  atomicAdd(&sums[cur * 512 + c], acc);
}

// ---------------- mean + fc1(elu) + fc2, one block ----------------
__global__ __launch_bounds__(512) void mlp_k(const float* __restrict__ sums,
                                             const int* __restrict__ bstart,
                                             const int* __restrict__ bend,
                                             const float* __restrict__ w1,
                                             const float* __restrict__ b1,
                                             const float* __restrict__ w2,
                                             const float* __restrict__ b2,
                                             float* __restrict__ out) {
  __shared__ float gm[16 * 512];
  __shared__ float t1[16 * 32];
  int t = threadIdx.x;
  for (int i = t; i < 16 * 512; i += 512) {
    int b = i >> 9;
    float c = (float)(bend[b] - bstart[b]);
    gm[i] = sums[i] / fmaxf(c, 1.f);
  }
  __syncthreads();
  {
    int b = t >> 5, j = t & 31;
    float s = b1[j];
    for (int k = 0; k < 512; k++) s += gm[(b << 9) + k] * w1[k * 32 + j];
    t1[t] = elu_f(s);
  }
  __syncthreads();
  if (t < 160) {
    int b = t / 10, j = t - b * 10;
    float s = b2[j];
#pragma unroll
    for (int k = 0; k < 32; k++) s += t1[b * 32 + k] * w2[k * 10 + j];
    out[t] = s;
  }
}

extern "C" void kernel_launch(void* const* d_in, const int* in_sizes, int n_in,
                              void* d_out, int out_size, void* d_ws, size_t ws_size,
                              hipStream_t stream) {
  const float* x   = (const float*)d_in[0];
  const int*   ei  = (const int*)d_in[1];
  const int* batch = (const int*)d_in[2];
  const float* W1  = (const float*)d_in[3];
  const float* as1 = (const float*)d_in[4];
  const float* ad1 = (const float*)d_in[5];
  const float* b1  = (const float*)d_in[6];
  const float* W2  = (const float*)d_in[7];
  const float* as2 = (const float*)d_in[8];
  const float* ad2 = (const float*)d_in[9];
  const float* b2  = (const float*)d_in[10];
  const float* f1w = (const float*)d_in[11];
  const float* f1b = (const float*)d_in[12];
  const float* f2w = (const float*)d_in[13];
  const float* f2b = (const float*)d_in[14];
  float* out = (float*)d_out;

  const int Nn = in_sizes[2];      // 10000
  const int E = in_sizes[1] / 2;   // 160000
  const int Etot = E + Nn;         // self loops appended

  // ---- workspace layout (4B words, 64-word aligned) ----
  size_t off = 0;
  auto alloc = [&](size_t elems) { size_t o = off; off += (elems + 63) & ~(size_t)63; return o; };
  int* wsi = (int*)d_ws;
  float* wsf = (float*)d_ws;

  size_t o_deg  = alloc(Nn);
  size_t o_pool = alloc(16 * 512);
  size_t o_as1  = alloc((size_t)Nn * 8);
  size_t o_ad1  = alloc((size_t)Nn * 8);
  size_t o_as2  = alloc((size_t)Nn * 8);
  size_t o_ad2  = alloc((size_t)Nn * 8);
  size_t zero_words = off;               // accumulated-into buffers -> zero each call
  size_t o_bst  = alloc(64);
  size_t o_ben  = alloc(64);
  size_t o_offs = alloc(Nn + 1);
  size_t o_cur  = alloc(Nn);
  size_t o_src  = alloc(Etot);
  size_t o_dst  = alloc(Etot);
  size_t o_psrc = alloc(Etot);
  size_t o_xb   = alloc((size_t)Nn * 128 / 2);   // x bf16  [N,128]
  size_t o_w1t  = alloc(1024 * 128 / 2);         // W1^T bf16 [1024,128]
  size_t o_w2t  = alloc(512 * 1024 / 2);         // W2^T bf16 [512,1024]
  size_t o_h    = alloc((size_t)Nn * 1024 / 2);  // h bf16 [N,1024] (layer2 uses first half)
  size_t o_g    = alloc((size_t)Nn * 1024);      // g1 bf16 (first half) then g2 fp32

  ushort_t* xb  = (ushort_t*)(wsi + o_xb);
  ushort_t* w1t = (ushort_t*)(wsi + o_w1t);
  ushort_t* w2t = (ushort_t*)(wsi + o_w2t);
  ushort_t* hb  = (ushort_t*)(wsi + o_h);
  ushort_t* g1b = (ushort_t*)(wsi + o_g);

  int eb = (Etot + 255) / 256;

  init_k<<<(1024 * 512 + 255) / 256, 256, 0, stream>>>(wsi, (int)zero_words, x, xb,
                                                       W1, w1t, W2, w2t, Nn * 128 / 4);
  prep_k<<<eb, 256, 0, stream>>>(ei, wsi + o_src, wsi + o_dst, wsi + o_deg,
                                 batch, wsi + o_bst, wsi + o_ben, E, Nn);
  scan_k<<<1, 1024, 0, stream>>>(wsi + o_deg, wsi + o_offs, wsi + o_cur, Nn);
  scatter_k<<<eb, 256, 0, stream>>>(wsi + o_src, wsi + o_dst, wsi + o_cur,
                                    wsi + o_psrc, Etot);

  // ---- layer 1: 128 -> 8x128 ----
  mfma_gemm_k<<<dim3(1024 / 128, (Nn + 127) / 128), 256, 0, stream>>>(
      xb, w1t, hb, as1, ad1, wsf + o_as1, wsf + o_ad1, Nn, 1024, 128, 7);
  aggregate_k<1024, 7, 128, ushort_t><<<Nn, 128, 0, stream>>>(
      hb, wsf + o_as1, wsf + o_ad1, wsi + o_offs, wsi + o_psrc, b1, g1b);

  // ---- layer 2: 1024 -> 8x64 ----
  mfma_gemm_k<<<dim3(512 / 128, (Nn + 127) / 128), 256, 0, stream>>>(
      g1b, w2t, hb, as2, ad2, wsf + o_as2, wsf + o_ad2, Nn, 512, 1024, 6);
  aggregate_k<512, 6, 64, float><<<Nn, 64, 0, stream>>>(
      hb, wsf + o_as2, wsf + o_ad2, wsi + o_offs, wsi + o_psrc, b2, wsf + o_g);

  // ---- pool + MLP ----
  pool_k<<<dim3(2, (Nn + 49) / 50), 256, 0, stream>>>(wsf + o_g, batch, wsf + o_pool, Nn);
  mlp_k<<<1, 512, 0, stream>>>(wsf + o_pool, wsi + o_bst, wsi + o_ben, f1w, f1b, f2w, f2b, out);
}

// Round 15
// 274.088 us; speedup vs baseline: 1.0346x; 1.0346x over previous
//
#include <hip/hip_runtime.h>
#include <math.h>

#define HEADS 8
#define NEG 0.2f

typedef unsigned short ushort_t;
typedef __attribute__((ext_vector_type(8))) short short8;
typedef float f32x4 __attribute__((ext_vector_type(4)));

__device__ inline ushort_t f2bf(float f) {
  union { float f; unsigned u; } v; v.f = f;
  unsigned r = (v.u + 0x7FFF + ((v.u >> 16) & 1)) >> 16;  // RNE
  return (ushort_t)r;
}

__device__ inline float4 bf4(uint2 v) {
  union { unsigned u; float f; } a, b, c, d;
  a.u = v.x << 16; b.u = v.x & 0xffff0000u;
  c.u = v.y << 16; d.u = v.y & 0xffff0000u;
  return make_float4(a.f, b.f, c.f, d.f);
}

// fast ELU: exp(v)-1 via hw v_exp_f32; |abs err| ~1e-7, fine vs 1.7e-3 threshold
__device__ inline float elu_f(float v) {
  return (v > 0.f) ? v : (__expf(v) - 1.f);
}

// ------- fused init: zero accum buffers + x->bf16 + W1/W2 -> transposed bf16 -------
__global__ void init_k(int* __restrict__ ws, int zero_words,
                       const float* __restrict__ x, ushort_t* __restrict__ xb,
                       const float* __restrict__ W1, ushort_t* __restrict__ w1t,
                       const float* __restrict__ W2, ushort_t* __restrict__ w2t,
                       int nx4) {
  int i = blockIdx.x * blockDim.x + threadIdx.x;
  if (i < zero_words) ws[i] = 0;
  if (i < nx4) {
    float4 v = ((const float4*)x)[i];
    ushort_t o[4] = {f2bf(v.x), f2bf(v.y), f2bf(v.z), f2bf(v.w)};
    *(uint2*)&xb[i * 4] = *(uint2*)o;
  }
  if (i < 128 * 1024) {  // W1 [128][1024] -> w1t [1024][128]
    int n = i >> 7, k = i & 127;
    w1t[i] = f2bf(W1[(size_t)k * 1024 + n]);
  }
  if (i < 1024 * 512) {  // W2 [1024][512] -> w2t [512][1024]
    int n = i >> 10, k = i & 1023;
    w2t[i] = f2bf(W2[(size_t)k * 512 + n]);
  }
}

// -- edge prep + degree count + batch bounds fused (batch sorted; no atomics) --
__global__ void prep_k(const int* __restrict__ ei, int* __restrict__ src,
                       int* __restrict__ dst, int* __restrict__ deg,
                       const int* __restrict__ batch, int* __restrict__ bstart,
                       int* __restrict__ bend, int E, int Nn) {
  int i = blockIdx.x * blockDim.x + threadIdx.x;
  if (i < Nn) {
    int b = batch[i];
    if (i == 0 || batch[i - 1] != b) bstart[b] = i;
    if (i == Nn - 1 || batch[i + 1] != b) bend[b] = i + 1;
  }
  if (i >= E + Nn) return;
  int s, d;
  if (i < E) { s = ei[i]; d = ei[E + i]; }
  else       { s = d = i - E; }
  src[i] = s;
  dst[i] = d;
  atomicAdd(&deg[d], 1);
}

// single-block scan over N, 4 elems/thread (4096/chunk), wave-shuffle based
__global__ __launch_bounds__(1024) void scan_k(const int* __restrict__ deg,
                                               int* __restrict__ offs,
                                               int* __restrict__ cursor, int Nn) {
  __shared__ int wtot[16];
  __shared__ int wexcl[16];
  __shared__ int soff_s;
  int t = threadIdx.x;
  int lane = t & 63, w = t >> 6;
  if (t == 0) soff_s = 0;
  __syncthreads();
  for (int base = 0; base < Nn; base += 4096) {
    int idx = base + 4 * t;
    int4 v = make_int4(0, 0, 0, 0);
    if (idx + 3 < Nn) v = *(const int4*)&deg[idx];
    else {
      if (idx < Nn)     v.x = deg[idx];
      if (idx + 1 < Nn) v.y = deg[idx + 1];
      if (idx + 2 < Nn) v.z = deg[idx + 2];
      if (idx + 3 < Nn) v.w = deg[idx + 3];
    }
    int s1 = v.x, s2 = s1 + v.y, s3 = s2 + v.z, s4 = s3 + v.w;
    int sc = s4;  // wave-inclusive scan of per-thread totals
#pragma unroll
    for (int o = 1; o < 64; o <<= 1) {
      int x = __shfl_up(sc, o);
      if (lane >= o) sc += x;
    }
    if (lane == 63) wtot[w] = sc;
    __syncthreads();
    if (w == 0) {
      int tv = (lane < 16) ? wtot[lane] : 0;
      int ts = tv;
#pragma unroll
      for (int o = 1; o < 16; o <<= 1) {
        int x = __shfl_up(ts, o);
        if (lane >= o) ts += x;
      }
      if (lane < 16) wexcl[lane] = ts - tv;
      if (lane == 15) wtot[15] = ts;  // chunk total
    }
    __syncthreads();
    int excl = soff_s + wexcl[w] + (sc - s4);
    int o0 = excl, o1 = excl + s1, o2 = excl + s2, o3 = excl + s3;
    if (idx < Nn)     { offs[idx] = o0;     cursor[idx] = o0; }
    if (idx + 1 < Nn) { offs[idx + 1] = o1; cursor[idx + 1] = o1; }
    if (idx + 2 < Nn) { offs[idx + 2] = o2; cursor[idx + 2] = o2; }
    if (idx + 3 < Nn) { offs[idx + 3] = o3; cursor[idx + 3] = o3; }
    int chunk_total = wtot[15];
    __syncthreads();
    if (t == 0) soff_s += chunk_total;
    __syncthreads();
  }
  if (t == 0) offs[Nn] = soff_s;
}

// scatter src values directly into CSR slot order (no perm indirection)
__global__ void scatter_k(const int* __restrict__ src, const int* __restrict__ dst,
                          int* __restrict__ cursor, int* __restrict__ psrc, int Etot) {
  int i = blockIdx.x * blockDim.x + threadIdx.x;
  if (i >= Etot) return;
  int p = atomicAdd(&cursor[dst[i]], 1);
  psrc[p] = src[i];
}

// ------- bf16 MFMA GEMM + fused alpha epilogue: Cb[M,N](bf16) = A @ Bt^T -------
// 128x128 tile, 256 threads (4 waves 2x2), BK=64 (2 k-steps of 16x16x32 MFMA),
// register-prefetch software pipeline.
#define LDA 72  // padded LDS row stride (bf16 elems), 144B rows, 16B aligned
__global__ __launch_bounds__(256) void mfma_gemm_k(const ushort_t* __restrict__ A,
                                                   const ushort_t* __restrict__ Bt,
                                                   ushort_t* __restrict__ Cb,
                                                   const float* __restrict__ att_s,
                                                   const float* __restrict__ att_d,
                                                   float* __restrict__ asrc,
                                                   float* __restrict__ adst,
                                                   int M, int N, int K, int CSHIFT) {
  __shared__ ushort_t As[128 * LDA];
  __shared__ ushort_t Bs[128 * LDA];
  int tid = threadIdx.x;
  int lane = tid & 63;
  int wave = tid >> 6;
  int wm = (wave >> 1) * 64, wn = (wave & 1) * 64;
  int bm = blockIdx.y * 128, bn = blockIdx.x * 128;
  int lrow = lane & 15, lq = lane >> 4;

  f32x4 acc[4][4];
#pragma unroll
  for (int i = 0; i < 4; i++)
#pragma unroll
    for (int j = 0; j < 4; j++) acc[i][j] = 0.f;

  int srow = tid >> 2;          // 0..63
  int skc = (tid & 3) * 8;      // k elem offset within first 32 of BK

  int gr0 = min(bm + srow, M - 1);
  int gr1 = min(bm + srow + 64, M - 1);
  const ushort_t* pa0 = &A[(size_t)gr0 * K + skc];
  const ushort_t* pa1 = &A[(size_t)gr1 * K + skc];
  const ushort_t* pb0 = &Bt[(size_t)(bn + srow) * K + skc];
  const ushort_t* pb1 = &Bt[(size_t)(bn + srow + 64) * K + skc];

  short8 va0 = *(const short8*)pa0;
  short8 va1 = *(const short8*)(pa0 + 32);
  short8 va2 = *(const short8*)pa1;
  short8 va3 = *(const short8*)(pa1 + 32);
  short8 vb0 = *(const short8*)pb0;
  short8 vb1 = *(const short8*)(pb0 + 32);
  short8 vb2 = *(const short8*)pb1;
  short8 vb3 = *(const short8*)(pb1 + 32);

  for (int k0 = 0; k0 < K; k0 += 64) {
    __syncthreads();  // previous iter's fragment reads done before overwrite
    *(short8*)&As[srow * LDA + skc] = va0;
    *(short8*)&As[srow * LDA + 32 + skc] = va1;
    *(short8*)&As[(srow + 64) * LDA + skc] = va2;
    *(short8*)&As[(srow + 64) * LDA + 32 + skc] = va3;
    *(short8*)&Bs[srow * LDA + skc] = vb0;
    *(short8*)&Bs[srow * LDA + 32 + skc] = vb1;
    *(short8*)&Bs[(srow + 64) * LDA + skc] = vb2;
    *(short8*)&Bs[(srow + 64) * LDA + 32 + skc] = vb3;
    __syncthreads();
    if (k0 + 64 < K) {  // prefetch next chunk; completes during MFMA below
      int kn = k0 + 64;
      va0 = *(const short8*)(pa0 + kn);
      va1 = *(const short8*)(pa0 + kn + 32);
      va2 = *(const short8*)(pa1 + kn);
      va3 = *(const short8*)(pa1 + kn + 32);
      vb0 = *(const short8*)(pb0 + kn);
      vb1 = *(const short8*)(pb0 + kn + 32);
      vb2 = *(const short8*)(pb1 + kn);
      vb3 = *(const short8*)(pb1 + kn + 32);
    }
#pragma unroll
    for (int ks = 0; ks < 2; ks++) {
      short8 af[4], bfr[4];
#pragma unroll
      for (int t = 0; t < 4; t++) {
        af[t]  = *(const short8*)&As[(wm + t * 16 + lrow) * LDA + ks * 32 + lq * 8];
        bfr[t] = *(const short8*)&Bs[(wn + t * 16 + lrow) * LDA + ks * 32 + lq * 8];
      }
#pragma unroll
      for (int i = 0; i < 4; i++)
#pragma unroll
        for (int j = 0; j < 4; j++)
          acc[i][j] = __builtin_amdgcn_mfma_f32_16x16x32_bf16(af[i], bfr[j], acc[i][j], 0, 0, 0);
    }
  }

  // ---- fused alpha partials (fp32, pre-rounding) ----
  {
    int hh = (bn + wn) >> CSHIFT;
    float avs[4], avd[4];
#pragma unroll
    for (int j = 0; j < 4; j++) {
      int col = bn + wn + j * 16 + lrow;  // att [H][N/H] flat == column index
      avs[j] = att_s[col];
      avd[j] = att_d[col];
    }
#pragma unroll
    for (int i = 0; i < 4; i++) {
#pragma unroll
      for (int r = 0; r < 4; r++) {
        float ps = 0.f, pd = 0.f;
#pragma unroll
        for (int j = 0; j < 4; j++) {
          float v = acc[i][j][r];
          ps += v * avs[j];
          pd += v * avd[j];
        }
#pragma unroll
        for (int o = 1; o < 16; o <<= 1) {
          ps += __shfl_xor(ps, o);
          pd += __shfl_xor(pd, o);
        }
        int row = bm + wm + i * 16 + lq * 4 + r;
        if (lrow == 0 && row < M) {
          atomicAdd(&asrc[row * HEADS + hh], ps);
          atomicAdd(&adst[row * HEADS + hh], pd);
        }
      }
    }
  }

  // ---- bf16 store ----
#pragma unroll
  for (int i = 0; i < 4; i++) {
    int row0 = bm + wm + i * 16 + lq * 4;  // C/D: col=lane&15, row=(lane>>4)*4+reg
#pragma unroll
    for (int j = 0; j < 4; j++) {
      int col = bn + wn + j * 16 + lrow;
#pragma unroll
      for (int r = 0; r < 4; r++) {
        int row = row0 + r;
        if (row < M) Cb[(size_t)row * N + col] = f2bf(acc[i][j][r]);
      }
    }
  }
}

// ---- CSR aggregation: barrier-free, LDS-free, software-pipelined uint2 gathers ----
// NSPLIT blocks per node; block handles CPB = F/NSPLIT channels with BT = CPB/4
// threads (4 consecutive channels each). psrc reads are block-uniform (HW
// broadcast); softmax weight via hw v_exp_f32 (__expf); next batch's src ids
// prefetched while 16 gathers are in flight. Wave count > per-thread width
// (R14 lesson: 8-ch/uint4 halved waves and regressed).
template <int F, int CSHIFT, int BT, int NSPLIT, typename OT>
__global__ __launch_bounds__(BT) void aggregate_k(const ushort_t* __restrict__ hb,
                                                  const float* __restrict__ asrc,
                                                  const float* __restrict__ adst,
                                                  const int* __restrict__ offs,
                                                  const int* __restrict__ psrc,
                                                  const float* __restrict__ bias,
                                                  OT* __restrict__ out) {
  constexpr int CPB = F / NSPLIT;
  static_assert(CPB == 4 * BT, "CPB/thread mismatch");
  int nb = blockIdx.x;
  int n = nb / NSPLIT;
  int coff = (nb - n * NSPLIT) * CPB;
  int t = threadIdx.x;
  int c0 = coff + 4 * t;
  int hh = c0 >> CSHIFT;
  float adn = adst[n * HEADS + hh];
  int e0 = offs[n], e1 = offs[n + 1];
  float4 acc = make_float4(0.f, 0.f, 0.f, 0.f);
  float wsum = 0.f;

  int i = e0;
  int s[8];
  if (i + 8 <= e1) {
#pragma unroll
    for (int u = 0; u < 8; u++) s[u] = psrc[i + u];
  }
  while (i + 8 <= e1) {
    uint2 r[8];
    float av[8];
#pragma unroll
    for (int u = 0; u < 8; u++) r[u] = *(const uint2*)&hb[(size_t)s[u] * F + c0];
#pragma unroll
    for (int u = 0; u < 8; u++) av[u] = asrc[s[u] * HEADS + hh];
    i += 8;
    bool more = (i + 8 <= e1);
    int sn[8];
#pragma unroll
    for (int u = 0; u < 8; u++) sn[u] = more ? psrc[i + u] : 0;
#pragma unroll
    for (int u = 0; u < 8; u++) {
      float v = av[u] + adn;
      v = (v > 0.f) ? v : NEG * v;  // leaky_relu(0.2)
      float w = __expf(v);          // hw v_exp_f32; shift-invariant softmax
      float4 f = bf4(r[u]);
      wsum += w;
      acc.x += w * f.x;
      acc.y += w * f.y;
      acc.z += w * f.z;
      acc.w += w * f.w;
    }
#pragma unroll
    for (int u = 0; u < 8; u++) s[u] = sn[u];
  }
  for (; i < e1; i++) {
    int ss = psrc[i];
    float v = asrc[ss * HEADS + hh] + adn;
    v = (v > 0.f) ? v : NEG * v;
    float w = __expf(v);
    float4 f = bf4(*(const uint2*)&hb[(size_t)ss * F + c0]);
    wsum += w;
    acc.x += w * f.x; acc.y += w * f.y;
    acc.z += w * f.z; acc.w += w * f.w;
  }

  float inv = 1.f / wsum;
  float v0 = elu_f(acc.x * inv + bias[c0]);
  float v1 = elu_f(acc.y * inv + bias[c0 + 1]);
  float v2 = elu_f(acc.z * inv + bias[c0 + 2]);
  float v3 = elu_f(acc.w * inv + bias[c0 + 3]);
  if (sizeof(OT) == 2) {
    unsigned p0 = (unsigned)f2bf(v0) | ((unsigned)f2bf(v1) << 16);
    unsigned p1 = (unsigned)f2bf(v2) | ((unsigned)f2bf(v3) << 16);
    *(uint2*)&((ushort_t*)out)[(size_t)n * F + c0] = make_uint2(p0, p1);
  } else {
    *(float4*)&((float*)out)[(size_t)n * F + c0] = make_float4(v0, v1, v2, v3);
  }
}

__global__ __launch_bounds__(256) void pool_k(const float* __restrict__ g,
                                              const int* __restrict__ batch,
                                              float* __restrict__ sums, int Nn) {
  int c = blockIdx.x * 256 + threadIdx.x;  // 0..511
  int n0 = blockIdx.y * 50;
  int n1 = min(n0 + 50, Nn);
  if (n0 >= n1) return;
  float acc = 0.f;
  int cur = batch[n0];
  for (int n = n0; n < n1; n++) {
    int b = batch[n];
    if (b != cur) { atomicAdd(&sums[cur * 512 + c], acc); acc = 0.f; cur = b; }
    acc += g[(size_t)n * 512 + c];
  }
  atomicAdd(&sums[cur * 512 + c], acc);
}

// ---------------- mean + fc1(elu) + fc2, one block ----------------
__global__ __launch_bounds__(512) void mlp_k(const float* __restrict__ sums,
                                             const int* __restrict__ bstart,
                                             const int* __restrict__ bend,
                                             const float* __restrict__ w1,
                                             const float* __restrict__ b1,
                                             const float* __restrict__ w2,
                                             const float* __restrict__ b2,
                                             float* __restrict__ out) {
  __shared__ float gm[16 * 512];
  __shared__ float t1[16 * 32];
  int t = threadIdx.x;
  for (int i = t; i < 16 * 512; i += 512) {
    int b = i >> 9;
    float c = (float)(bend[b] - bstart[b]);
    gm[i] = sums[i] / fmaxf(c, 1.f);
  }
  __syncthreads();
  {
    int b = t >> 5, j = t & 31;
    float s = b1[j];
    for (int k = 0; k < 512; k++) s += gm[(b << 9) + k] * w1[k * 32 + j];
    t1[t] = elu_f(s);
  }
  __syncthreads();
  if (t < 160) {
    int b = t / 10, j = t - b * 10;
    float s = b2[j];
#pragma unroll
    for (int k = 0; k < 32; k++) s += t1[b * 32 + k] * w2[k * 10 + j];
    out[t] = s;
  }
}

extern "C" void kernel_launch(void* const* d_in, const int* in_sizes, int n_in,
                              void* d_out, int out_size, void* d_ws, size_t ws_size,
                              hipStream_t stream) {
  const float* x   = (const float*)d_in[0];
  const int*   ei  = (const int*)d_in[1];
  const int* batch = (const int*)d_in[2];
  const float* W1  = (const float*)d_in[3];
  const float* as1 = (const float*)d_in[4];
  const float* ad1 = (const float*)d_in[5];
  const float* b1  = (const float*)d_in[6];
  const float* W2  = (const float*)d_in[7];
  const float* as2 = (const float*)d_in[8];
  const float* ad2 = (const float*)d_in[9];
  const float* b2  = (const float*)d_in[10];
  const float* f1w = (const float*)d_in[11];
  const float* f1b = (const float*)d_in[12];
  const float* f2w = (const float*)d_in[13];
  const float* f2b = (const float*)d_in[14];
  float* out = (float*)d_out;

  const int Nn = in_sizes[2];      // 10000
  const int E = in_sizes[1] / 2;   // 160000
  const int Etot = E + Nn;         // self loops appended

  // ---- workspace layout (4B words, 64-word aligned) ----
  size_t off = 0;
  auto alloc = [&](size_t elems) { size_t o = off; off += (elems + 63) & ~(size_t)63; return o; };
  int* wsi = (int*)d_ws;
  float* wsf = (float*)d_ws;

  size_t o_deg  = alloc(Nn);
  size_t o_pool = alloc(16 * 512);
  size_t o_as1  = alloc((size_t)Nn * 8);
  size_t o_ad1  = alloc((size_t)Nn * 8);
  size_t o_as2  = alloc((size_t)Nn * 8);
  size_t o_ad2  = alloc((size_t)Nn * 8);
  size_t zero_words = off;               // accumulated-into buffers -> zero each call
  size_t o_bst  = alloc(64);
  size_t o_ben  = alloc(64);
  size_t o_offs = alloc(Nn + 1);
  size_t o_cur  = alloc(Nn);
  size_t o_src  = alloc(Etot);
  size_t o_dst  = alloc(Etot);
  size_t o_psrc = alloc(Etot);
  size_t o_xb   = alloc((size_t)Nn * 128 / 2);   // x bf16  [N,128]
  size_t o_w1t  = alloc(1024 * 128 / 2);         // W1^T bf16 [1024,128]
  size_t o_w2t  = alloc(512 * 1024 / 2);         // W2^T bf16 [512,1024]
  size_t o_h    = alloc((size_t)Nn * 1024 / 2);  // h bf16 [N,1024] (layer2 uses first half)
  size_t o_g    = alloc((size_t)Nn * 1024);      // g1 bf16 (first half) then g2 fp32

  ushort_t* xb  = (ushort_t*)(wsi + o_xb);
  ushort_t* w1t = (ushort_t*)(wsi + o_w1t);
  ushort_t* w2t = (ushort_t*)(wsi + o_w2t);
  ushort_t* hb  = (ushort_t*)(wsi + o_h);
  ushort_t* g1b = (ushort_t*)(wsi + o_g);

  int eb = (Etot + 255) / 256;

  init_k<<<(1024 * 512 + 255) / 256, 256, 0, stream>>>(wsi, (int)zero_words, x, xb,
                                                       W1, w1t, W2, w2t, Nn * 128 / 4);
  prep_k<<<eb, 256, 0, stream>>>(ei, wsi + o_src, wsi + o_dst, wsi + o_deg,
                                 batch, wsi + o_bst, wsi + o_ben, E, Nn);
  scan_k<<<1, 1024, 0, stream>>>(wsi + o_deg, wsi + o_offs, wsi + o_cur, Nn);
  scatter_k<<<eb, 256, 0, stream>>>(wsi + o_src, wsi + o_dst, wsi + o_cur,
                                    wsi + o_psrc, Etot);

  // ---- layer 1: 128 -> 8x128 ----
  mfma_gemm_k<<<dim3(1024 / 128, (Nn + 127) / 128), 256, 0, stream>>>(
      xb, w1t, hb, as1, ad1, wsf + o_as1, wsf + o_ad1, Nn, 1024, 128, 7);
  aggregate_k<1024, 7, 128, 2, ushort_t><<<Nn * 2, 128, 0, stream>>>(
      hb, wsf + o_as1, wsf + o_ad1, wsi + o_offs, wsi + o_psrc, b1, g1b);

  // ---- layer 2: 1024 -> 8x64 ----
  mfma_gemm_k<<<dim3(512 / 128, (Nn + 127) / 128), 256, 0, stream>>>(
      g1b, w2t, hb, as2, ad2, wsf + o_as2, wsf + o_ad2, Nn, 512, 1024, 6);
  aggregate_k<512, 6, 64, 2, float><<<Nn * 2, 64, 0, stream>>>(
      hb, wsf + o_as2, wsf + o_ad2, wsi + o_offs, wsi + o_psrc, b2, wsf + o_g);

  // ---- pool + MLP ----
  pool_k<<<dim3(2, (Nn + 49) / 50), 256, 0, stream>>>(wsf + o_g, batch, wsf + o_pool, Nn);
  mlp_k<<<1, 512, 0, stream>>>(wsf + o_pool, wsi + o_bst, wsi + o_ben, f1w, f1b, f2w, f2b, out);
}

// Round 16
// 271.136 us; speedup vs baseline: 1.0459x; 1.0109x over previous
//
#include <hip/hip_runtime.h>
#include <math.h>

#define HEADS 8
#define NEG 0.2f

typedef unsigned short ushort_t;
typedef __attribute__((ext_vector_type(8))) short short8;
typedef float f32x4 __attribute__((ext_vector_type(4)));

__device__ inline ushort_t f2bf(float f) {
  union { float f; unsigned u; } v; v.f = f;
  unsigned r = (v.u + 0x7FFF + ((v.u >> 16) & 1)) >> 16;  // RNE
  return (ushort_t)r;
}

__device__ inline float4 bf4(uint2 v) {
  union { unsigned u; float f; } a, b, c, d;
  a.u = v.x << 16; b.u = v.x & 0xffff0000u;
  c.u = v.y << 16; d.u = v.y & 0xffff0000u;
  return make_float4(a.f, b.f, c.f, d.f);
}

// fast ELU: exp(v)-1 via hw v_exp_f32; |abs err| ~1e-7, fine vs 1.7e-3 threshold
__device__ inline float elu_f(float v) {
  return (v > 0.f) ? v : (__expf(v) - 1.f);
}

// ---- fused init: LDS-tiled W transpose (coalesced both ways) + zero + x->bf16 ----
// blocks 0..639: 32x32 transpose tiles (W1: 128 tiles, W2: 512 tiles)
// blocks 640.. : zero accum region + cast x to bf16
__global__ __launch_bounds__(256) void init_k(int* __restrict__ ws, int zero_words,
                                              const float* __restrict__ x,
                                              ushort_t* __restrict__ xb,
                                              const float* __restrict__ W1,
                                              ushort_t* __restrict__ w1t,
                                              const float* __restrict__ W2,
                                              ushort_t* __restrict__ w2t, int nx4) {
  __shared__ float tile[32][33];
  int blk = blockIdx.x;
  if (blk < 640) {
    const float* W; ushort_t* Wt; int K, N, tk, tn;
    if (blk < 128) { W = W1; Wt = w1t; K = 128; N = 1024; tk = blk >> 5; tn = blk & 31; }
    else { W = W2; Wt = w2t; K = 1024; N = 512; int t = blk - 128; tk = t >> 4; tn = t & 15; }
    int tx = threadIdx.x & 31, ty = threadIdx.x >> 5;  // 32 x 8
    int k0 = tk * 32, n0 = tn * 32;
#pragma unroll
    for (int r = 0; r < 4; r++)
      tile[ty + r * 8][tx] = W[(size_t)(k0 + ty + r * 8) * N + n0 + tx];  // coalesced read
    __syncthreads();
#pragma unroll
    for (int r = 0; r < 4; r++)
      Wt[(size_t)(n0 + ty + r * 8) * K + k0 + tx] = f2bf(tile[tx][ty + r * 8]);  // coalesced write
  } else {
    int i = (blk - 640) * 256 + threadIdx.x;
    if (i < zero_words) ws[i] = 0;
    if (i < nx4) {
      float4 v = ((const float4*)x)[i];
      ushort_t o[4] = {f2bf(v.x), f2bf(v.y), f2bf(v.z), f2bf(v.w)};
      *(uint2*)&xb[i * 4] = *(uint2*)o;
    }
  }
}

// -- edge prep + degree count + batch bounds fused (batch sorted; no atomics) --
__global__ void prep_k(const int* __restrict__ ei, int* __restrict__ src,
                       int* __restrict__ dst, int* __restrict__ deg,
                       const int* __restrict__ batch, int* __restrict__ bstart,
                       int* __restrict__ bend, int E, int Nn) {
  int i = blockIdx.x * blockDim.x + threadIdx.x;
  if (i < Nn) {
    int b = batch[i];
    if (i == 0 || batch[i - 1] != b) bstart[b] = i;
    if (i == Nn - 1 || batch[i + 1] != b) bend[b] = i + 1;
  }
  if (i >= E + Nn) return;
  int s, d;
  if (i < E) { s = ei[i]; d = ei[E + i]; }
  else       { s = d = i - E; }
  src[i] = s;
  dst[i] = d;
  atomicAdd(&deg[d], 1);
}

// single-block scan over N, 4 elems/thread (4096/chunk), wave-shuffle based
__global__ __launch_bounds__(1024) void scan_k(const int* __restrict__ deg,
                                               int* __restrict__ offs,
                                               int* __restrict__ cursor, int Nn) {
  __shared__ int wtot[16];
  __shared__ int wexcl[16];
  __shared__ int soff_s;
  int t = threadIdx.x;
  int lane = t & 63, w = t >> 6;
  if (t == 0) soff_s = 0;
  __syncthreads();
  for (int base = 0; base < Nn; base += 4096) {
    int idx = base + 4 * t;
    int4 v = make_int4(0, 0, 0, 0);
    if (idx + 3 < Nn) v = *(const int4*)&deg[idx];
    else {
      if (idx < Nn)     v.x = deg[idx];
      if (idx + 1 < Nn) v.y = deg[idx + 1];
      if (idx + 2 < Nn) v.z = deg[idx + 2];
      if (idx + 3 < Nn) v.w = deg[idx + 3];
    }
    int s1 = v.x, s2 = s1 + v.y, s3 = s2 + v.z, s4 = s3 + v.w;
    int sc = s4;  // wave-inclusive scan of per-thread totals
#pragma unroll
    for (int o = 1; o < 64; o <<= 1) {
      int x = __shfl_up(sc, o);
      if (lane >= o) sc += x;
    }
    if (lane == 63) wtot[w] = sc;
    __syncthreads();
    if (w == 0) {
      int tv = (lane < 16) ? wtot[lane] : 0;
      int ts = tv;
#pragma unroll
      for (int o = 1; o < 16; o <<= 1) {
        int x = __shfl_up(ts, o);
        if (lane >= o) ts += x;
      }
      if (lane < 16) wexcl[lane] = ts - tv;
      if (lane == 15) wtot[15] = ts;  // chunk total
    }
    __syncthreads();
    int excl = soff_s + wexcl[w] + (sc - s4);
    int o0 = excl, o1 = excl + s1, o2 = excl + s2, o3 = excl + s3;
    if (idx < Nn)     { offs[idx] = o0;     cursor[idx] = o0; }
    if (idx + 1 < Nn) { offs[idx + 1] = o1; cursor[idx + 1] = o1; }
    if (idx + 2 < Nn) { offs[idx + 2] = o2; cursor[idx + 2] = o2; }
    if (idx + 3 < Nn) { offs[idx + 3] = o3; cursor[idx + 3] = o3; }
    int chunk_total = wtot[15];
    __syncthreads();
    if (t == 0) soff_s += chunk_total;
    __syncthreads();
  }
  if (t == 0) offs[Nn] = soff_s;
}

// scatter src values directly into CSR slot order (no perm indirection)
__global__ void scatter_k(const int* __restrict__ src, const int* __restrict__ dst,
                          int* __restrict__ cursor, int* __restrict__ psrc, int Etot) {
  int i = blockIdx.x * blockDim.x + threadIdx.x;
  if (i >= Etot) return;
  int p = atomicAdd(&cursor[dst[i]], 1);
  psrc[p] = src[i];
}

// ------- bf16 MFMA GEMM + fused alpha epilogue: Cb[M,N](bf16) = A @ Bt^T -------
// 128x128 tile, 256 threads (4 waves 2x2), BK=64 (2 k-steps of 16x16x32 MFMA),
// register-prefetch software pipeline.
#define LDA 72  // padded LDS row stride (bf16 elems), 144B rows, 16B aligned
__global__ __launch_bounds__(256) void mfma_gemm_k(const ushort_t* __restrict__ A,
                                                   const ushort_t* __restrict__ Bt,
                                                   ushort_t* __restrict__ Cb,
                                                   const float* __restrict__ att_s,
                                                   const float* __restrict__ att_d,
                                                   float* __restrict__ asrc,
                                                   float* __restrict__ adst,
                                                   int M, int N, int K, int CSHIFT) {
  __shared__ ushort_t As[128 * LDA];
  __shared__ ushort_t Bs[128 * LDA];
  int tid = threadIdx.x;
  int lane = tid & 63;
  int wave = tid >> 6;
  int wm = (wave >> 1) * 64, wn = (wave & 1) * 64;
  int bm = blockIdx.y * 128, bn = blockIdx.x * 128;
  int lrow = lane & 15, lq = lane >> 4;

  f32x4 acc[4][4];
#pragma unroll
  for (int i = 0; i < 4; i++)
#pragma unroll
    for (int j = 0; j < 4; j++) acc[i][j] = 0.f;

  int srow = tid >> 2;          // 0..63
  int skc = (tid & 3) * 8;      // k elem offset within first 32 of BK

  int gr0 = min(bm + srow, M - 1);
  int gr1 = min(bm + srow + 64, M - 1);
  const ushort_t* pa0 = &A[(size_t)gr0 * K + skc];
  const ushort_t* pa1 = &A[(size_t)gr1 * K + skc];
  const ushort_t* pb0 = &Bt[(size_t)(bn + srow) * K + skc];
  const ushort_t* pb1 = &Bt[(size_t)(bn + srow + 64) * K + skc];

  short8 va0 = *(const short8*)pa0;
  short8 va1 = *(const short8*)(pa0 + 32);
  short8 va2 = *(const short8*)pa1;
  short8 va3 = *(const short8*)(pa1 + 32);
  short8 vb0 = *(const short8*)pb0;
  short8 vb1 = *(const short8*)(pb0 + 32);
  short8 vb2 = *(const short8*)pb1;
  short8 vb3 = *(const short8*)(pb1 + 32);

  for (int k0 = 0; k0 < K; k0 += 64) {
    __syncthreads();  // previous iter's fragment reads done before overwrite
    *(short8*)&As[srow * LDA + skc] = va0;
    *(short8*)&As[srow * LDA + 32 + skc] = va1;
    *(short8*)&As[(srow + 64) * LDA + skc] = va2;
    *(short8*)&As[(srow + 64) * LDA + 32 + skc] = va3;
    *(short8*)&Bs[srow * LDA + skc] = vb0;
    *(short8*)&Bs[srow * LDA + 32 + skc] = vb1;
    *(short8*)&Bs[(srow + 64) * LDA + skc] = vb2;
    *(short8*)&Bs[(srow + 64) * LDA + 32 + skc] = vb3;
    __syncthreads();
    if (k0 + 64 < K) {  // prefetch next chunk; completes during MFMA below
      int kn = k0 + 64;
      va0 = *(const short8*)(pa0 + kn);
      va1 = *(const short8*)(pa0 + kn + 32);
      va2 = *(const short8*)(pa1 + kn);
      va3 = *(const short8*)(pa1 + kn + 32);
      vb0 = *(const short8*)(pb0 + kn);
      vb1 = *(const short8*)(pb0 + kn + 32);
      vb2 = *(const short8*)(pb1 + kn);
      vb3 = *(const short8*)(pb1 + kn + 32);
    }
#pragma unroll
    for (int ks = 0; ks < 2; ks++) {
      short8 af[4], bfr[4];
#pragma unroll
      for (int t = 0; t < 4; t++) {
        af[t]  = *(const short8*)&As[(wm + t * 16 + lrow) * LDA + ks * 32 + lq * 8];
        bfr[t] = *(const short8*)&Bs[(wn + t * 16 + lrow) * LDA + ks * 32 + lq * 8];
      }
#pragma unroll
      for (int i = 0; i < 4; i++)
#pragma unroll
        for (int j = 0; j < 4; j++)
          acc[i][j] = __builtin_amdgcn_mfma_f32_16x16x32_bf16(af[i], bfr[j], acc[i][j], 0, 0, 0);
    }
  }

  // ---- fused alpha partials (fp32, pre-rounding) ----
  {
    int hh = (bn + wn) >> CSHIFT;
    float avs[4], avd[4];
#pragma unroll
    for (int j = 0; j < 4; j++) {
      int col = bn + wn + j * 16 + lrow;  // att [H][N/H] flat == column index
      avs[j] = att_s[col];
      avd[j] = att_d[col];
    }
#pragma unroll
    for (int i = 0; i < 4; i++) {
#pragma unroll
      for (int r = 0; r < 4; r++) {
        float ps = 0.f, pd = 0.f;
#pragma unroll
        for (int j = 0; j < 4; j++) {
          float v = acc[i][j][r];
          ps += v * avs[j];
          pd += v * avd[j];
        }
#pragma unroll
        for (int o = 1; o < 16; o <<= 1) {
          ps += __shfl_xor(ps, o);
          pd += __shfl_xor(pd, o);
        }
        int row = bm + wm + i * 16 + lq * 4 + r;
        if (lrow == 0 && row < M) {
          atomicAdd(&asrc[row * HEADS + hh], ps);
          atomicAdd(&adst[row * HEADS + hh], pd);
        }
      }
    }
  }

  // ---- bf16 store ----
#pragma unroll
  for (int i = 0; i < 4; i++) {
    int row0 = bm + wm + i * 16 + lq * 4;  // C/D: col=lane&15, row=(lane>>4)*4+reg
#pragma unroll
    for (int j = 0; j < 4; j++) {
      int col = bn + wn + j * 16 + lrow;
#pragma unroll
      for (int r = 0; r < 4; r++) {
        int row = row0 + r;
        if (row < M) Cb[(size_t)row * N + col] = f2bf(acc[i][j][r]);
      }
    }
  }
}

// ---- CSR aggregation: barrier-free, LDS-free, software-pipelined uint2 gathers ----
// NSPLIT blocks per node; block handles CPB = F/NSPLIT channels with BT = CPB/4
// threads (4 consecutive channels each). psrc reads are block-uniform (HW
// broadcast); softmax weight via hw v_exp_f32 (__expf); next batch's src ids
// prefetched while 16 gathers are in flight. Wave count > per-thread width
// (R14 lesson: 8-ch/uint4 halved waves and regressed).
template <int F, int CSHIFT, int BT, int NSPLIT, typename OT>
__global__ __launch_bounds__(BT) void aggregate_k(const ushort_t* __restrict__ hb,
                                                  const float* __restrict__ asrc,
                                                  const float* __restrict__ adst,
                                                  const int* __restrict__ offs,
                                                  const int* __restrict__ psrc,
                                                  const float* __restrict__ bias,
                                                  OT* __restrict__ out) {
  constexpr int CPB = F / NSPLIT;
  static_assert(CPB == 4 * BT, "CPB/thread mismatch");
  int nb = blockIdx.x;
  int n = nb / NSPLIT;
  int coff = (nb - n * NSPLIT) * CPB;
  int t = threadIdx.x;
  int c0 = coff + 4 * t;
  int hh = c0 >> CSHIFT;
  float adn = adst[n * HEADS + hh];
  int e0 = offs[n], e1 = offs[n + 1];
  float4 acc = make_float4(0.f, 0.f, 0.f, 0.f);
  float wsum = 0.f;

  int i = e0;
  int s[8];
  if (i + 8 <= e1) {
#pragma unroll
    for (int u = 0; u < 8; u++) s[u] = psrc[i + u];
  }
  while (i + 8 <= e1) {
    uint2 r[8];
    float av[8];
#pragma unroll
    for (int u = 0; u < 8; u++) r[u] = *(const uint2*)&hb[(size_t)s[u] * F + c0];
#pragma unroll
    for (int u = 0; u < 8; u++) av[u] = asrc[s[u] * HEADS + hh];
    i += 8;
    bool more = (i + 8 <= e1);
    int sn[8];
#pragma unroll
    for (int u = 0; u < 8; u++) sn[u] = more ? psrc[i + u] : 0;
#pragma unroll
    for (int u = 0; u < 8; u++) {
      float v = av[u] + adn;
      v = (v > 0.f) ? v : NEG * v;  // leaky_relu(0.2)
      float w = __expf(v);          // hw v_exp_f32; shift-invariant softmax
      float4 f = bf4(r[u]);
      wsum += w;
      acc.x += w * f.x;
      acc.y += w * f.y;
      acc.z += w * f.z;
      acc.w += w * f.w;
    }
#pragma unroll
    for (int u = 0; u < 8; u++) s[u] = sn[u];
  }
  for (; i < e1; i++) {
    int ss = psrc[i];
    float v = asrc[ss * HEADS + hh] + adn;
    v = (v > 0.f) ? v : NEG * v;
    float w = __expf(v);
    float4 f = bf4(*(const uint2*)&hb[(size_t)ss * F + c0]);
    wsum += w;
    acc.x += w * f.x; acc.y += w * f.y;
    acc.z += w * f.z; acc.w += w * f.w;
  }

  float inv = 1.f / wsum;
  float v0 = elu_f(acc.x * inv + bias[c0]);
  float v1 = elu_f(acc.y * inv + bias[c0 + 1]);
  float v2 = elu_f(acc.z * inv + bias[c0 + 2]);
  float v3 = elu_f(acc.w * inv + bias[c0 + 3]);
  if (sizeof(OT) == 2) {
    unsigned p0 = (unsigned)f2bf(v0) | ((unsigned)f2bf(v1) << 16);
    unsigned p1 = (unsigned)f2bf(v2) | ((unsigned)f2bf(v3) << 16);
    *(uint2*)&((ushort_t*)out)[(size_t)n * F + c0] = make_uint2(p0, p1);
  } else {
    *(float4*)&((float*)out)[(size_t)n * F + c0] = make_float4(v0, v1, v2, v3);
  }
}

__global__ __launch_bounds__(256) void pool_k(const float* __restrict__ g,
                                              const int* __restrict__ batch,
                                              float* __restrict__ sums, int Nn) {
  int c = blockIdx.x * 256 + threadIdx.x;  // 0..511
  int n0 = blockIdx.y * 50;
  int n1 = min(n0 + 50, Nn);
  if (n0 >= n1) return;
  float acc = 0.f;
  int cur = batch[n0];
  for (int n = n0; n < n1; n++) {
    int b = batch[n];
    if (b != cur) { atomicAdd(&sums[cur * 512 + c], acc); acc = 0.f; cur = b; }
    acc += g[(size_t)n * 512 + c];
  }
  atomicAdd(&sums[cur * 512 + c], acc);
}

// ---------------- mean + fc1(elu) + fc2, one block ----------------
__global__ __launch_bounds__(512) void mlp_k(const float* __restrict__ sums,
                                             const int* __restrict__ bstart,
                                             const int* __restrict__ bend,
                                             const float* __restrict__ w1,
                                             const float* __restrict__ b1,
                                             const float* __restrict__ w2,
                                             const float* __restrict__ b2,
                                             float* __restrict__ out) {
  __shared__ float gm[16 * 512];
  __shared__ float t1[16 * 32];
  int t = threadIdx.x;
  for (int i = t; i < 16 * 512; i += 512) {
    int b = i >> 9;
    float c = (float)(bend[b] - bstart[b]);
    gm[i] = sums[i] / fmaxf(c, 1.f);
  }
  __syncthreads();
  {
    int b = t >> 5, j = t & 31;
    float s = b1[j];
    for (int k = 0; k < 512; k++) s += gm[(b << 9) + k] * w1[k * 32 + j];
    t1[t] = elu_f(s);
  }
  __syncthreads();
  if (t < 160) {
    int b = t / 10, j = t - b * 10;
    float s = b2[j];
#pragma unroll
    for (int k = 0; k < 32; k++) s += t1[b * 32 + k] * w2[k * 10 + j];
    out[t] = s;
  }
}

extern "C" void kernel_launch(void* const* d_in, const int* in_sizes, int n_in,
                              void* d_out, int out_size, void* d_ws, size_t ws_size,
                              hipStream_t stream) {
  const float* x   = (const float*)d_in[0];
  const int*   ei  = (const int*)d_in[1];
  const int* batch = (const int*)d_in[2];
  const float* W1  = (const float*)d_in[3];
  const float* as1 = (const float*)d_in[4];
  const float* ad1 = (const float*)d_in[5];
  const float* b1  = (const float*)d_in[6];
  const float* W2  = (const float*)d_in[7];
  const float* as2 = (const float*)d_in[8];
  const float* ad2 = (const float*)d_in[9];
  const float* b2  = (const float*)d_in[10];
  const float* f1w = (const float*)d_in[11];
  const float* f1b = (const float*)d_in[12];
  const float* f2w = (const float*)d_in[13];
  const float* f2b = (const float*)d_in[14];
  float* out = (float*)d_out;

  const int Nn = in_sizes[2];      // 10000
  const int E = in_sizes[1] / 2;   // 160000
  const int Etot = E + Nn;         // self loops appended

  // ---- workspace layout (4B words, 64-word aligned) ----
  size_t off = 0;
  auto alloc = [&](size_t elems) { size_t o = off; off += (elems + 63) & ~(size_t)63; return o; };
  int* wsi = (int*)d_ws;
  float* wsf = (float*)d_ws;

  size_t o_deg  = alloc(Nn);
  size_t o_pool = alloc(16 * 512);
  size_t o_as1  = alloc((size_t)Nn * 8);
  size_t o_ad1  = alloc((size_t)Nn * 8);
  size_t o_as2  = alloc((size_t)Nn * 8);
  size_t o_ad2  = alloc((size_t)Nn * 8);
  size_t zero_words = off;               // accumulated-into buffers -> zero each call
  size_t o_bst  = alloc(64);
  size_t o_ben  = alloc(64);
  size_t o_offs = alloc(Nn + 1);
  size_t o_cur  = alloc(Nn);
  size_t o_src  = alloc(Etot);
  size_t o_dst  = alloc(Etot);
  size_t o_psrc = alloc(Etot);
  size_t o_xb   = alloc((size_t)Nn * 128 / 2);   // x bf16  [N,128]
  size_t o_w1t  = alloc(1024 * 128 / 2);         // W1^T bf16 [1024,128]
  size_t o_w2t  = alloc(512 * 1024 / 2);         // W2^T bf16 [512,1024]
  size_t o_h    = alloc((size_t)Nn * 1024 / 2);  // h bf16 [N,1024] (layer2 uses first half)
  size_t o_g    = alloc((size_t)Nn * 1024);      // g1 bf16 (first half) then g2 fp32

  ushort_t* xb  = (ushort_t*)(wsi + o_xb);
  ushort_t* w1t = (ushort_t*)(wsi + o_w1t);
  ushort_t* w2t = (ushort_t*)(wsi + o_w2t);
  ushort_t* hb  = (ushort_t*)(wsi + o_h);
  ushort_t* g1b = (ushort_t*)(wsi + o_g);

  int eb = (Etot + 255) / 256;

  int nx4 = Nn * 128 / 4;
  int ep_work = (int)((zero_words > (size_t)nx4 ? zero_words : (size_t)nx4));
  int init_blocks = 640 + (ep_work + 255) / 256;
  init_k<<<init_blocks, 256, 0, stream>>>(wsi, (int)zero_words, x, xb,
                                          W1, w1t, W2, w2t, nx4);
  prep_k<<<eb, 256, 0, stream>>>(ei, wsi + o_src, wsi + o_dst, wsi + o_deg,
                                 batch, wsi + o_bst, wsi + o_ben, E, Nn);
  scan_k<<<1, 1024, 0, stream>>>(wsi + o_deg, wsi + o_offs, wsi + o_cur, Nn);
  scatter_k<<<eb, 256, 0, stream>>>(wsi + o_src, wsi + o_dst, wsi + o_cur,
                                    wsi + o_psrc, Etot);

  // ---- layer 1: 128 -> 8x128 ----
  mfma_gemm_k<<<dim3(1024 / 128, (Nn + 127) / 128), 256, 0, stream>>>(
      xb, w1t, hb, as1, ad1, wsf + o_as1, wsf + o_ad1, Nn, 1024, 128, 7);
  aggregate_k<1024, 7, 128, 2, ushort_t><<<Nn * 2, 128, 0, stream>>>(
      hb, wsf + o_as1, wsf + o_ad1, wsi + o_offs, wsi + o_psrc, b1, g1b);

  // ---- layer 2: 1024 -> 8x64 ----
  mfma_gemm_k<<<dim3(512 / 128, (Nn + 127) / 128), 256, 0, stream>>>(
      g1b, w2t, hb, as2, ad2, wsf + o_as2, wsf + o_ad2, Nn, 512, 1024, 6);
  aggregate_k<512, 6, 64, 2, float><<<Nn * 2, 64, 0, stream>>>(
      hb, wsf + o_as2, wsf + o_ad2, wsi + o_offs, wsi + o_psrc, b2, wsf + o_g);

  // ---- pool + MLP ----
  pool_k<<<dim3(2, (Nn + 49) / 50), 256, 0, stream>>>(wsf + o_g, batch, wsf + o_pool, Nn);
  mlp_k<<<1, 512, 0, stream>>>(wsf + o_pool, wsi + o_bst, wsi + o_ben, f1w, f1b, f2w, f2b, out);
}